// Round 1
// baseline (503.366 us; speedup 1.0000x reference)
//
#include <hip/hip_runtime.h>

typedef __attribute__((ext_vector_type(8))) __bf16 bf16x8;
typedef __attribute__((ext_vector_type(4))) float f32x4;
typedef __attribute__((ext_vector_type(4))) unsigned int u32x4;
typedef __attribute__((ext_vector_type(4))) unsigned short u16x4;
typedef __attribute__((ext_vector_type(8))) unsigned short u16x8;

__device__ __forceinline__ unsigned short f2bf(float x) {
  unsigned u = __builtin_bit_cast(unsigned, x);
  u += 0x7fffu + ((u >> 16) & 1u);
  return (unsigned short)(u >> 16);
}
__device__ __forceinline__ float bf2f(unsigned short h) {
  unsigned u = ((unsigned)h) << 16;
  return __builtin_bit_cast(float, u);
}
__device__ __forceinline__ bf16x8 ld_frag(const unsigned short* p) {
  u32x4 u = *(const u32x4*)p;
  return __builtin_bit_cast(bf16x8, u);
}
__device__ __forceinline__ void gload_lds16(const unsigned short* g, unsigned short* l) {
  __builtin_amdgcn_global_load_lds(
      (const __attribute__((address_space(1))) void*)g,
      (__attribute__((address_space(3))) void*)l, 16, 0, 0);
}

// ---------------- f32 -> bf16 conversion (vectorized) ----------------
__global__ __launch_bounds__(256) void cvt_bf16(const float* __restrict__ in,
                                                unsigned short* __restrict__ out, int n4) {
  int i = blockIdx.x * 256 + threadIdx.x;
  if (i >= n4) return;
  f32x4 v = *((const f32x4*)in + i);
  u16x4 o;
  #pragma unroll
  for (int j = 0; j < 4; ++j) o[j] = f2bf(v[j]);
  *((u16x4*)out + i) = o;
}

// ---------------- GEMM: C[M,N] = A[M,K] * B[N,K]^T, bf16 in, f32 acc ----------------
// 128x128 tile, BK=32, 4 waves (2x2, 64x64 each), global_load_lds staging with
// XOR chunk swizzle (kc ^= (row>>1)&3) for conflict-free ds_read_b128.
template <int WRITE_BF16>
__global__ __launch_bounds__(256) void gemm_bt(const unsigned short* __restrict__ A,
                                               const unsigned short* __restrict__ B,
                                               void* __restrict__ Cv,
                                               int M, int N, int K) {
  __shared__ __align__(16) unsigned short As[128 * 32];
  __shared__ __align__(16) unsigned short Bs[128 * 32];
  const int tid = threadIdx.x;
  const int wave = tid >> 6, lane = tid & 63;
  const int g = lane >> 4, r = lane & 15;
  const int wm = (wave >> 1) * 64, wn = (wave & 1) * 64;
  const size_t bm0 = (size_t)blockIdx.x * 128, bn0 = (size_t)blockIdx.y * 128;
  f32x4 acc[4][4] = {};
  for (int kt = 0; kt < K; kt += 32) {
    #pragma unroll
    for (int it = 0; it < 2; ++it) {
      const int cb = it * 256 + wave * 64;
      const int c = cb + lane;
      const int row = c >> 2;
      const int kc = (c & 3) ^ ((row >> 1) & 3);
      gload_lds16(A + (bm0 + row) * (size_t)K + kt + kc * 8, &As[cb * 8]);
      gload_lds16(B + (bn0 + row) * (size_t)K + kt + kc * 8, &Bs[cb * 8]);
    }
    __syncthreads();
    bf16x8 af[4], bf[4];
    #pragma unroll
    for (int i = 0; i < 4; ++i) {
      const int ra = wm + i * 16 + r;
      af[i] = ld_frag(&As[ra * 32 + ((g ^ ((ra >> 1) & 3)) * 8)]);
      const int rb = wn + i * 16 + r;
      bf[i] = ld_frag(&Bs[rb * 32 + ((g ^ ((rb >> 1) & 3)) * 8)]);
    }
    #pragma unroll
    for (int mi = 0; mi < 4; ++mi)
      #pragma unroll
      for (int ni = 0; ni < 4; ++ni)
        acc[mi][ni] = __builtin_amdgcn_mfma_f32_16x16x32_bf16(af[mi], bf[ni], acc[mi][ni], 0, 0, 0);
    __syncthreads();
  }
  #pragma unroll
  for (int mi = 0; mi < 4; ++mi)
    #pragma unroll
    for (int ni = 0; ni < 4; ++ni)
      #pragma unroll
      for (int rr = 0; rr < 4; ++rr) {
        const size_t idx = (bm0 + wm + mi * 16 + g * 4 + rr) * (size_t)N + (bn0 + wn + ni * 16 + r);
        if (WRITE_BF16) ((unsigned short*)Cv)[idx] = f2bf(acc[mi][ni][rr]);
        else            ((float*)Cv)[idx] = acc[mi][ni][rr];
      }
}

// ---------------- RoPE in-place on Q (heads 0..31) and K (heads 32..39) ----------------
__global__ __launch_bounds__(256) void rope_qk(unsigned short* __restrict__ qkv,
                                               const float* __restrict__ cs,
                                               const float* __restrict__ sn) {
  const int t = blockIdx.x * 256 + threadIdx.x;   // B*S*40*48 = 7,864,320 exact
  const int d = t % 48;
  const int rest = t / 48;
  const int head = rest % 40;
  const int row = rest / 40;                      // b*2048+s
  const size_t base = (size_t)row * 4608 + head * 96 + d;
  const float x1 = bf2f(qkv[base]);
  const float x2 = bf2f(qkv[base + 48]);
  const int cb = row * 96 + d;
  const float c1 = cs[cb], s1 = sn[cb], c2 = cs[cb + 48], s2 = sn[cb + 48];
  qkv[base]      = f2bf(x1 * c1 - x2 * s1);
  qkv[base + 48] = f2bf(x2 * c2 + x1 * s2);
}

// ---------------- V transpose: qkv[b,s,3840+kvh*96+d] -> vt[b,kvh,d,s] ----------------
__global__ __launch_bounds__(256) void vtrans(const unsigned short* __restrict__ qkv,
                                              unsigned short* __restrict__ vt) {
  __shared__ __align__(16) unsigned short T[64 * 104];
  const int s0 = blockIdx.x * 64;
  const int kvh = blockIdx.y, b = blockIdx.z;
  const int tid = threadIdx.x;
  #pragma unroll
  for (int it = 0; it < 3; ++it) {
    const int c = it * 256 + tid;
    const int sr = c / 12, d0 = (c % 12) * 8;
    *(u32x4*)&T[sr * 104 + d0] =
        *(const u32x4*)&qkv[(size_t)(b * 2048 + s0 + sr) * 4608 + 3840 + kvh * 96 + d0];
  }
  __syncthreads();
  #pragma unroll
  for (int it = 0; it < 3; ++it) {
    const int c = it * 256 + tid;
    const int dr = c >> 3, k0 = (c & 7) * 8;
    u16x8 o;
    #pragma unroll
    for (int j = 0; j < 8; ++j) o[j] = T[(k0 + j) * 104 + dr];
    *(u16x8*)&vt[((size_t)(b * 8 + kvh) * 96 + dr) * 2048 + s0 + k0] = o;
  }
}

// ---------------- Flash attention, causal GQA, swapped QK^T ----------------
// Block: 4 waves, each owns 32 q-rows. KV tile = 64. S^T = K*Q^T so each lane's
// softmax state (m,l) is for its own q column; P^T staged per-wave in LDS.
__global__ __launch_bounds__(256) void attn_fwd(const unsigned short* __restrict__ qkv,
                                                const unsigned short* __restrict__ vt,
                                                unsigned short* __restrict__ ctx) {
  __shared__ __align__(16) unsigned short SMEM[22784];  // Ks 64x104 | Vs 96x72 | Ps 4x32x72
  unsigned short* Ks = SMEM;
  unsigned short* Vs = SMEM + 6656;
  unsigned short* Ps = SMEM + 13568;
  const int qt = blockIdx.x, h = blockIdx.y, b = blockIdx.z;
  const int kvh = h >> 2;
  const int tid = threadIdx.x;
  const int wave = tid >> 6, lane = tid & 63;
  const int g = lane >> 4, r = lane & 15;
  const int q0 = qt * 128 + wave * 32;
  const float scale = 0.10206207261596577f;  // 1/sqrt(96)

  bf16x8 qf[2][3];
  #pragma unroll
  for (int qb = 0; qb < 2; ++qb)
    #pragma unroll
    for (int dk = 0; dk < 3; ++dk)
      qf[qb][dk] = ld_frag(&qkv[(size_t)(b * 2048 + q0 + qb * 16 + r) * 4608 + h * 96 + dk * 32 + g * 8]);

  f32x4 o[6][2] = {};
  float m_[2] = {-1e30f, -1e30f};
  float l_[2] = {0.f, 0.f};
  const int nt = qt * 2 + 2;

  for (int t = 0; t < nt; ++t) {
    const int kv0 = t * 64;
    #pragma unroll
    for (int it = 0; it < 3; ++it) {
      const int c = it * 256 + tid;
      const int kr = c / 12, d0 = (c % 12) * 8;
      *(u32x4*)&Ks[kr * 104 + d0] =
          *(const u32x4*)&qkv[(size_t)(b * 2048 + kv0 + kr) * 4608 + 3072 + kvh * 96 + d0];
      const int dr = c >> 3, k0 = (c & 7) * 8;
      *(u32x4*)&Vs[dr * 72 + k0] =
          *(const u32x4*)&vt[((size_t)(b * 8 + kvh) * 96 + dr) * 2048 + kv0 + k0];
    }
    __syncthreads();

    if (kv0 <= q0 + 31) {  // wave has at least one unmasked element in this tile
      f32x4 st[4][2] = {};
      #pragma unroll
      for (int dk = 0; dk < 3; ++dk) {
        bf16x8 af[4];
        #pragma unroll
        for (int kb = 0; kb < 4; ++kb)
          af[kb] = ld_frag(&Ks[(kb * 16 + r) * 104 + dk * 32 + g * 8]);
        #pragma unroll
        for (int kb = 0; kb < 4; ++kb)
          #pragma unroll
          for (int qb = 0; qb < 2; ++qb)
            st[kb][qb] = __builtin_amdgcn_mfma_f32_16x16x32_bf16(af[kb], qf[qb][dk], st[kb][qb], 0, 0, 0);
      }
      // scale + causal mask (k_abs <= q_abs)
      if (kv0 + 63 > q0) {
        #pragma unroll
        for (int kb = 0; kb < 4; ++kb)
          #pragma unroll
          for (int qb = 0; qb < 2; ++qb)
            #pragma unroll
            for (int rr = 0; rr < 4; ++rr) {
              const int ka = kv0 + kb * 16 + g * 4 + rr;
              const int qa = q0 + qb * 16 + r;
              const float s = st[kb][qb][rr] * scale;
              st[kb][qb][rr] = (ka <= qa) ? s : -1e30f;
            }
      } else {
        #pragma unroll
        for (int kb = 0; kb < 4; ++kb)
          #pragma unroll
          for (int qb = 0; qb < 2; ++qb)
            #pragma unroll
            for (int rr = 0; rr < 4; ++rr)
              st[kb][qb][rr] *= scale;
      }
      // online softmax (per lane: its q column)
      #pragma unroll
      for (int qb = 0; qb < 2; ++qb) {
        float mx = st[0][qb][0];
        #pragma unroll
        for (int kb = 0; kb < 4; ++kb)
          #pragma unroll
          for (int rr = 0; rr < 4; ++rr) mx = fmaxf(mx, st[kb][qb][rr]);
        mx = fmaxf(mx, __shfl_xor(mx, 16));
        mx = fmaxf(mx, __shfl_xor(mx, 32));
        const float mnew = fmaxf(m_[qb], mx);
        const float corr = __expf(m_[qb] - mnew);
        m_[qb] = mnew;
        float rs = 0.f;
        #pragma unroll
        for (int kb = 0; kb < 4; ++kb)
          #pragma unroll
          for (int rr = 0; rr < 4; ++rr) {
            const float p = __expf(st[kb][qb][rr] - mnew);
            st[kb][qb][rr] = p;
            rs += p;
          }
        rs += __shfl_xor(rs, 16);
        rs += __shfl_xor(rs, 32);
        l_[qb] = l_[qb] * corr + rs;
        #pragma unroll
        for (int db = 0; db < 6; ++db) o[db][qb] *= corr;
      }
      // P[q][k] (bf16) to per-wave LDS
      #pragma unroll
      for (int kb = 0; kb < 4; ++kb)
        #pragma unroll
        for (int qb = 0; qb < 2; ++qb) {
          u16x4 w;
          #pragma unroll
          for (int rr = 0; rr < 4; ++rr) w[rr] = f2bf(st[kb][qb][rr]);
          *(u16x4*)&Ps[wave * 2304 + (qb * 16 + r) * 72 + kb * 16 + g * 4] = w;
        }
      // O^T += V^T * P^T
      #pragma unroll
      for (int kk = 0; kk < 2; ++kk) {
        bf16x8 pb[2];
        #pragma unroll
        for (int qb = 0; qb < 2; ++qb)
          pb[qb] = ld_frag(&Ps[wave * 2304 + (qb * 16 + r) * 72 + kk * 32 + g * 8]);
        #pragma unroll
        for (int db = 0; db < 6; ++db) {
          const bf16x8 va = ld_frag(&Vs[(db * 16 + r) * 72 + kk * 32 + g * 8]);
          #pragma unroll
          for (int qb = 0; qb < 2; ++qb)
            o[db][qb] = __builtin_amdgcn_mfma_f32_16x16x32_bf16(va, pb[qb], o[db][qb], 0, 0, 0);
        }
      }
    }
    __syncthreads();
  }

  // epilogue: normalize, transpose through LDS (reuse SMEM), coalesced bf16 stores
  const float inv_l[2] = {1.f / l_[0], 1.f / l_[1]};
  unsigned short* obuf = SMEM + wave * 3328;  // 32 x 104 per wave
  #pragma unroll
  for (int db = 0; db < 6; ++db)
    #pragma unroll
    for (int qb = 0; qb < 2; ++qb) {
      u16x4 w;
      #pragma unroll
      for (int rr = 0; rr < 4; ++rr) w[rr] = f2bf(o[db][qb][rr] * inv_l[qb]);
      *(u16x4*)&obuf[(qb * 16 + r) * 104 + db * 16 + g * 4] = w;
    }
  #pragma unroll
  for (int it = 0; it < 6; ++it) {
    const int c = it * 64 + lane;
    const int qr = c / 12, d0 = (c % 12) * 8;
    *(u32x4*)&ctx[(size_t)(b * 2048 + q0 + qr) * 3072 + h * 96 + d0] =
        *(const u32x4*)&obuf[qr * 104 + d0];
  }
}

extern "C" void kernel_launch(void* const* d_in, const int* in_sizes, int n_in,
                              void* d_out, int out_size, void* d_ws, size_t ws_size,
                              hipStream_t stream) {
  const float* hs   = (const float*)d_in[0];
  const float* cosp = (const float*)d_in[1];
  const float* sinp = (const float*)d_in[2];
  const float* wqkv = (const float*)d_in[4];
  const float* wo   = (const float*)d_in[5];
  float* out = (float*)d_out;

  // workspace layout (bf16 elems): qkv 18,874,368 | hsb 12,582,912 | wqb 14,155,776
  // after GEMM1: hsb region reused as vt (3,145,728) + wob (9,437,184); wqb as ctx.
  unsigned short* qkv = (unsigned short*)d_ws;
  unsigned short* hsb = qkv + 18874368;
  unsigned short* wqb = hsb + 12582912;
  unsigned short* vt  = hsb;
  unsigned short* wob = hsb + 3145728;
  unsigned short* ctx = wqb;

  cvt_bf16<<<12288, 256, 0, stream>>>(hs,   hsb, 3145728);
  cvt_bf16<<<13824, 256, 0, stream>>>(wqkv, wqb, 3538944);
  gemm_bt<1><<<dim3(32, 36), 256, 0, stream>>>(hsb, wqb, (void*)qkv, 4096, 4608, 3072);
  rope_qk<<<30720, 256, 0, stream>>>(qkv, cosp, sinp);
  vtrans<<<dim3(32, 8, 2), 256, 0, stream>>>(qkv, vt);
  cvt_bf16<<<9216, 256, 0, stream>>>(wo, wob, 2359296);
  attn_fwd<<<dim3(16, 32, 2), 256, 0, stream>>>(qkv, vt, ctx);
  gemm_bt<0><<<dim3(32, 24), 256, 0, stream>>>(ctx, wob, (void*)out, 4096, 3072, 3072);
}